// Round 6
// baseline (462.072 us; speedup 1.0000x reference)
//
#include <hip/hip_runtime.h>
#include <hip/hip_bf16.h>

// LGCN2: N=10000 nodes, RP=16, E=LW=64, R=NT=8000 edges, C=16, NREL=50.
// Round 6: R5 structure with the k_hgg LDS-layout bug fixed (the rp-stride-274
// padded layout aliased all 16 rp slabs; now natural [rp][hh][c] 64KB with
// q-rotated hh order -> 2-way bank conflicts = free).
// Stage-2 via g[n][rp][c] = w2[rp]^T h[n]; generic edges bucketed by output
// row np in k_lat idle lanes; k_gather: one wave per np, plain store.

#define N_     10000
#define RP_    16
#define E_     64
#define R_     8000
#define NT_    8000
#define C_     16
#define BK_    32              // s-bucket capacity (max s-degree ~7)
#define BK2_   96              // np-bucket capacity (E[np=0] ~38, margin 2.5x)

// ---- workspace layout (4-byte units) ----
// colsum  [0,       160000)  f  (zeroed)
// rowsum  [160000,  320000)  f  (zeroed)
// cnt     [320000,  330000)  i  (zeroed)
// cnt2    [330000,  340000)  i  (zeroed)
// order2  [340000,  660000)  i  (t | o<<13)
// bucket2 [660000, 1620000)  i  (t | r<<13 | rp<<17)
// lat1t   [1620000,1748000)  f  [t*16+r]
// lat2    [1748000,1876000)  f  [r*8000+t]
// g       [1876000,4436000)  f  [n*256 + rp*16 + c]
#define WS_ZERO_UNITS 340000

__global__ void k_lat(const float* __restrict__ nhots,
                      const float* __restrict__ w1a, const float* __restrict__ b1a,
                      const float* __restrict__ w1b, const float* __restrict__ b1b,
                      const float* __restrict__ w2a, const float* __restrict__ b2a,
                      const float* __restrict__ w2b, const float* __restrict__ b2b,
                      const int* __restrict__ hind, const int* __restrict__ vind,
                      float* __restrict__ lat1t, float* __restrict__ lat2,
                      float* __restrict__ colsum, float* __restrict__ rowsum,
                      int* __restrict__ cnt, int* __restrict__ order2,
                      int* __restrict__ cnt2, int* __restrict__ bucket2) {
    __shared__ float zb[4][128];
    __shared__ float r0[2];
    const int lane = threadIdx.x & 63;
    const int wv   = threadIdx.x >> 6;
    const int t    = blockIdx.x * 4 + wv;          // 2000*4 == 8000 exactly

    // --- sparse gather: scan first 256 columns (hot col < NREL=50) ---
    const float4 v = reinterpret_cast<const float4*>(nhots + (size_t)t * R_)[lane];
    float acc1 = 0.f, acc2 = 0.f;
    const float comp[4] = {v.x, v.y, v.z, v.w};
    #pragma unroll
    for (int c = 0; c < 4; ++c) {
        unsigned long long m = __ballot(comp[c] != 0.0f);
        while (m) {
            const int src = __ffsll(m) - 1;
            m &= m - 1;
            const float val = __shfl(comp[c], src);
            const int col = src * 4 + c;
            acc1 += val * w1a[col * 64 + lane];
            acc2 += val * w2a[col * 64 + lane];
        }
    }
    if (threadIdx.x == 0) { r0[0] = 0.f; r0[1] = 0.f; }
    zb[wv][lane]      = fmaxf(acc1 + b1a[lane], 0.f);
    zb[wv][64 + lane] = fmaxf(acc2 + b2a[lane], 0.f);
    __syncthreads();

    // --- 64->16 dense layer: lanes 0..15 do lat1, 16..31 do lat2 ---
    const int g = lane >> 4, r = lane & 15;
    float pre = 0.f;
    if (g < 2) {
        const float* wb = (g == 0) ? w1b : w2b;
        pre = ((g == 0) ? b1b : b2b)[r];
        const float* z = &zb[wv][g * 64];
        #pragma unroll
        for (int l = 0; l < 64; ++l) pre += z[l] * wb[l * 16 + r];
    }
    // --- softmax over the 16-lane group ---
    float mx = pre;
    #pragma unroll
    for (int m = 8; m >= 1; m >>= 1) mx = fmaxf(mx, __shfl_xor(mx, m, 16));
    const float e = expf(pre - mx);
    float s = e;
    #pragma unroll
    for (int m = 8; m >= 1; m >>= 1) s += __shfl_xor(s, m, 16);
    const float lt = e / s;

    const int s_t = hind[2 * t];                   // r=0 band: hrow == s[t]
    const int o_t = vind[2 * t + 1];               // r=0 band: vcol == o[t]
    if (g == 0) {
        lat1t[t * 16 + r] = lt;
        if (r) atomicAdd(colsum + o_t * r, lt);    // key hcol == o*r
        else   atomicAdd(&r0[0], lt);              // key-0 hotspot -> LDS pre-agg
    } else if (g == 1) {
        lat2[r * NT_ + t] = lt;
        if (r) atomicAdd(rowsum + s_t * r, lt);
        else   atomicAdd(&r0[1], lt);
    } else if (g == 2) {
        if (r == 0) {                              // s-bucket insert (for h gather)
            const int pos = atomicAdd(cnt + s_t, 1);
            order2[s_t * BK_ + pos] = t | (o_t << 13);
        } else {                                   // np-bucket insert (for out gather)
            const int q = s_t * r;                 // vrow
            const int rp = q / N_;
            const int np = q - rp * N_;
            const int pos = atomicAdd(cnt2 + np, 1);
            bucket2[np * BK2_ + pos] = t | (r << 13) | (rp << 17);
        }
    }
    __syncthreads();
    if (threadIdx.x == 0) atomicAdd(colsum, r0[0]);
    if (threadIdx.x == 1) atomicAdd(rowsum, r0[1]);
}

// Fused: h-row gather (h stays in registers) + g-table build.
// g[n*256 + rp*16 + c] = sum_h w2[rp,h,c] * relu(bias1[h] + sum_edges ...)
// 313 blocks * 32 nodes; each wave handles 8 nodes.
__global__ void k_hgg(const float* __restrict__ lat1t, const float* __restrict__ colsum,
                      const int* __restrict__ cnt, const int* __restrict__ order2,
                      const float* __restrict__ w1, const float* __restrict__ bias1,
                      const float* __restrict__ w2, float* __restrict__ g,
                      float* __restrict__ out) {
    __shared__ float sw2[16384];                   // natural [rp][hh][c], 64KB
    const int lane = threadIdx.x & 63;
    const int wv   = threadIdx.x >> 6;
    if (blockIdx.x == 0 && threadIdx.x < 16) out[threadIdx.x] = 0.f;  // row 0 init
    for (int i = threadIdx.x; i < 16384; i += 256) sw2[i] = w2[i];
    __syncthreads();

    const int q = lane >> 4, c = lane & 15;
    const int nbase = blockIdx.x * 32 + wv * 8;
    float u[8];
    #pragma unroll 1
    for (int i = 0; i < 8; ++i) {
        const int n = nbase + i;
        float acc = 0.f;
        if (n < N_) {
            const int m = cnt[n];
            for (int j = 0; j < m; ++j) {
                const int e = order2[n * BK_ + j];
                const int t = e & 8191, o_t = e >> 13;
                float ln = 0.f;
                if (lane < 16) ln = lat1t[t * 16 + lane] / colsum[o_t * lane];
                #pragma unroll
                for (int r = 0; r < 16; ++r)
                    acc += __shfl(ln, r) * w1[(o_t * r) * 64 + lane];
            }
            acc = fmaxf(acc + bias1[lane], 0.f);
        }
        u[i] = acc;
    }
    // g build: lane (q,c) owns rp = q*4+k. hh order rotated by q so each
    // ds_read's bank pattern is (j*16 + q*16 + c) mod 32 -> 2-way only (free).
    float a[8][4];
    #pragma unroll
    for (int i = 0; i < 8; ++i)
        #pragma unroll
        for (int k = 0; k < 4; ++k) a[i][k] = 0.f;
    for (int j = 0; j < 64; ++j) {
        const int hh = (j + q) & 63;
        float w4[4];
        #pragma unroll
        for (int k = 0; k < 4; ++k)
            w4[k] = sw2[(q * 4 + k) * 1024 + hh * 16 + c];
        #pragma unroll
        for (int i = 0; i < 8; ++i) {
            const float uh = __shfl(u[i], hh);
            #pragma unroll
            for (int k = 0; k < 4; ++k) a[i][k] += uh * w4[k];
        }
    }
    #pragma unroll 1
    for (int i = 0; i < 8; ++i) {
        const int n = nbase + i;
        if (n >= N_) break;
        #pragma unroll
        for (int k = 0; k < 4; ++k)
            g[n * 256 + (q * 4 + k) * 16 + c] = a[i][k];
    }
}

// Stage 2 gather. blocks 0..3: r0 band -> atomicAdd out[0..15].
// blocks 4..2503: one wave per np; register accumulate; one plain store.
__global__ void k_gather(const float* __restrict__ lat2, const float* __restrict__ rowsum,
                         const int* __restrict__ vind, const int* __restrict__ cnt2,
                         const int* __restrict__ bucket2, const float* __restrict__ g,
                         const float* __restrict__ bias2, float* __restrict__ out) {
    const int lane = threadIdx.x & 63;
    const int wv   = threadIdx.x >> 6;
    const int q = lane >> 4, c = lane & 15;

    if (blockIdx.x < 4) {                           // --- r0 band ---
        const int w = blockIdx.x * 4 + wv;          // 0..15, 500 t each
        float acc = 0.f;
        for (int t = w * 500 + q; t < (w + 1) * 500; t += 4) {
            const int o_t = vind[2 * t + 1];
            acc += lat2[t] * g[o_t * 256 + c];      // rp = 0 slab
        }
        acc += __shfl_xor(acc, 16);
        acc += __shfl_xor(acc, 32);
        if (q == 0) atomicAdd(&out[c], acc / rowsum[0]);
        return;
    }

    const int np = (blockIdx.x - 4) * 4 + wv;       // 2500*4 == 10000 exactly
    const int m2 = cnt2[np];
    float acc = 0.f;
    for (int j = q; j < m2; j += 4) {
        const int e = bucket2[np * BK2_ + j];
        const int t = e & 8191, r = (e >> 13) & 15, rp = (e >> 17) & 15;
        const float val = lat2[r * NT_ + t] / rowsum[rp * N_ + np];
        const int vc = vind[2 * t + 1];
        acc += val * g[vc * 256 + rp * 16 + c];
    }
    acc += __shfl_xor(acc, 16);
    acc += __shfl_xor(acc, 32);
    if (q == 0) {
        if (np == 0) atomicAdd(&out[c], acc + bias2[c]);
        else         out[np * 16 + c] = acc + bias2[c];
    }
}

extern "C" void kernel_launch(void* const* d_in, const int* in_sizes, int n_in,
                              void* d_out, int out_size, void* d_ws, size_t ws_size,
                              hipStream_t stream) {
    const float* nhots    = (const float*)d_in[0];
    const float* w1a      = (const float*)d_in[1];
    const float* b1a      = (const float*)d_in[2];
    const float* w1b      = (const float*)d_in[3];
    const float* b1b      = (const float*)d_in[4];
    const float* w2a      = (const float*)d_in[5];
    const float* b2a      = (const float*)d_in[6];
    const float* w2b      = (const float*)d_in[7];
    const float* b2b      = (const float*)d_in[8];
    const float* weights1 = (const float*)d_in[9];
    const float* bias1    = (const float*)d_in[10];
    const float* weights2 = (const float*)d_in[11];
    const float* bias2    = (const float*)d_in[12];
    const int*   hind     = (const int*)d_in[13];
    const int*   vind     = (const int*)d_in[14];
    float* out = (float*)d_out;

    float* ws      = (float*)d_ws;
    float* colsum  = ws;
    float* rowsum  = ws + 160000;
    int*   cnt     = (int*)(ws + 320000);
    int*   cnt2    = (int*)(ws + 330000);
    int*   order2  = (int*)(ws + 340000);
    int*   bucket2 = (int*)(ws + 660000);
    float* lat1t   = ws + 1620000;
    float* lat2    = ws + 1748000;
    float* gtab    = ws + 1876000;

    hipMemsetAsync(d_ws, 0, WS_ZERO_UNITS * sizeof(float), stream);
    k_lat<<<2000, 256, 0, stream>>>(nhots, w1a, b1a, w1b, b1b, w2a, b2a, w2b, b2b,
                                    hind, vind, lat1t, lat2, colsum, rowsum,
                                    cnt, order2, cnt2, bucket2);
    k_hgg<<<313, 256, 0, stream>>>(lat1t, colsum, cnt, order2, weights1, bias1,
                                   weights2, gtab, out);
    k_gather<<<2504, 256, 0, stream>>>(lat2, rowsum, vind, cnt2, bucket2, gtab,
                                       bias2, out);
}

// Round 7
// 447.473 us; speedup vs baseline: 1.0326x; 1.0326x over previous
//
#include <hip/hip_runtime.h>
#include <hip/hip_bf16.h>

// LGCN2: N=10000 nodes, RP=16, E=LW=64, R=NT=8000 edges, C=16, NREL=50.
// Round 7: revert to R4 structure (best measured) + two cuts:
//  - nhots scan 64 cols (NREL=50<64): one float/lane, single ballot, 2MB read.
//  - k_h2all 1024-thread blocks: 128 compute blocks -> w2 LDS staging L2
//    traffic 32MB -> 8MB; r0 band 16 blocks x 16 waves, ticket target 15.

#define N_     10000
#define RP_    16
#define E_     64
#define R_     8000
#define NT_    8000
#define C_     16
#define BK_    32              // s-bucket capacity; max s-degree (Poisson 0.8) << 32

// ---- workspace layout (4-byte units) ----
// colsum  [0,       160000)  f  (zeroed)
// rowsum  [160000,  320000)  f  (zeroed)
// h2r0    [320000,  320064)  f  (zeroed)
// cnt     [320064,  330064)  i  (zeroed)
// done    [330064,  330065)  i  (zeroed)
// order2  [330080,  650080)  i  (t | o<<13; guarded by cnt)
// hbuf    [650080, 1290080)  f  (written, no zero needed)
// lat1t   [1290080,1418080)  f  [t*16+r] layout (gather broadcast reads)
// lat2    [1418080,1546080)  f  [r*8000+t] k-order (stage-2 coalescing)
#define WS_ZERO_UNITS 330080

__global__ void k_lat(const float* __restrict__ nhots,
                      const float* __restrict__ w1a, const float* __restrict__ b1a,
                      const float* __restrict__ w1b, const float* __restrict__ b1b,
                      const float* __restrict__ w2a, const float* __restrict__ b2a,
                      const float* __restrict__ w2b, const float* __restrict__ b2b,
                      const int* __restrict__ hind, const int* __restrict__ vind,
                      float* __restrict__ lat1t, float* __restrict__ lat2,
                      float* __restrict__ colsum, float* __restrict__ rowsum,
                      int* __restrict__ cnt, int* __restrict__ order2,
                      float* __restrict__ out, const float* __restrict__ bias2) {
    __shared__ float zb[4][128];
    __shared__ float r0[2];
    const int lane = threadIdx.x & 63;
    const int wv   = threadIdx.x >> 6;
    const int t    = blockIdx.x * 4 + wv;          // 2000*4 == 8000 exactly

    // fused out-init: 2000 blocks * 80 == 160000 exactly
    if (threadIdx.x < 80) {
        const int i = blockIdx.x * 80 + threadIdx.x;
        out[i] = bias2[i & 15];
    }

    // --- sparse gather: scan first 64 columns (hot col < NREL=50 < 64) ---
    const float v = nhots[(size_t)t * R_ + lane];
    float acc1 = 0.f, acc2 = 0.f;
    unsigned long long m = __ballot(v != 0.0f);
    while (m) {
        const int src = __ffsll(m) - 1;
        m &= m - 1;
        const float val = __shfl(v, src);
        acc1 += val * w1a[src * 64 + lane];
        acc2 += val * w2a[src * 64 + lane];
    }
    if (threadIdx.x == 0) { r0[0] = 0.f; r0[1] = 0.f; }
    zb[wv][lane]      = fmaxf(acc1 + b1a[lane], 0.f);
    zb[wv][64 + lane] = fmaxf(acc2 + b2a[lane], 0.f);
    __syncthreads();

    // --- 64->16 dense layer: lanes 0..15 do lat1, 16..31 do lat2 ---
    const int g = lane >> 4, r = lane & 15;
    float pre = 0.f;
    if (g < 2) {
        const float* wb = (g == 0) ? w1b : w2b;
        pre = ((g == 0) ? b1b : b2b)[r];
        const float* z = &zb[wv][g * 64];
        #pragma unroll
        for (int l = 0; l < 64; ++l) pre += z[l] * wb[l * 16 + r];
    }
    // --- softmax over the 16-lane group ---
    float mx = pre;
    #pragma unroll
    for (int mm = 8; mm >= 1; mm >>= 1) mx = fmaxf(mx, __shfl_xor(mx, mm, 16));
    const float e = expf(pre - mx);
    float s = e;
    #pragma unroll
    for (int mm = 8; mm >= 1; mm >>= 1) s += __shfl_xor(s, mm, 16);
    const float lt = e / s;

    const int s_t = hind[2 * t];                   // r=0 band: hrow == s[t]
    const int o_t = vind[2 * t + 1];               // r=0 band: vcol == o[t]
    if (g == 0) {
        lat1t[t * 16 + r] = lt;
        if (r) atomicAdd(colsum + o_t * r, lt);    // key hcol == o*r
        else   atomicAdd(&r0[0], lt);              // key-0 hotspot -> LDS pre-agg
    } else if (g == 1) {
        lat2[r * NT_ + t] = lt;
        if (r) atomicAdd(rowsum + s_t * r, lt);
        else   atomicAdd(&r0[1], lt);
    } else if (g == 2 && r == 0) {                 // idle lane: bucket insert
        const int pos = atomicAdd(cnt + s_t, 1);
        order2[s_t * BK_ + pos] = t | (o_t << 13); // t < 8192
    }
    __syncthreads();
    if (threadIdx.x == 0) atomicAdd(colsum, r0[0]);
    if (threadIdx.x == 1) atomicAdd(rowsum, r0[1]);
}

// gather: one wave per node n; h[n,l] = relu(bias1[l] + sum_{t in n} sum_r
//   (lat1[r,t]/colsum[o_t*r]) * weights1[o_t*r, l])
__global__ void k_hg(const float* __restrict__ lat1t, const float* __restrict__ colsum,
                     const int* __restrict__ cnt, const int* __restrict__ order2,
                     const float* __restrict__ w1,
                     const float* __restrict__ bias1, float* __restrict__ hbuf) {
    const int lane = threadIdx.x & 63;
    const int n = blockIdx.x * 4 + (threadIdx.x >> 6);  // 2500*4 == 10000 exactly
    const int m = cnt[n];
    float acc = 0.f;
    for (int j = 0; j < m; ++j) {
        const int e = order2[n * BK_ + j];
        const int t   = e & 8191;
        const int o_t = e >> 13;
        float ln = 0.f;
        if (lane < 16) ln = lat1t[t * 16 + lane] / colsum[o_t * lane];
        #pragma unroll
        for (int r = 0; r < 16; ++r) {
            const float a = __shfl(ln, r);
            acc += a * w1[(o_t * r) * 64 + lane];   // coalesced 256B row
        }
    }
    hbuf[n * 64 + lane] = fmaxf(acc + bias1[lane], 0.f);
}

// Stage 2, one dispatch, 1024-thread blocks:
//  blocks 0..127  : generic edges (k>=8000), wave-per-edge. hbuf row loaded
//                   once coalesced; w2 in LDS (quarter-staggered shfl reduce).
//  blocks 128..143: r=0 band (16 waves each; 256 partials) block reduction
//                   into h2r0; LAST r0 block (ticket==15) applies w2[0]·h2r0.
__global__ void k_h2all(const float* __restrict__ lat2, const float* __restrict__ rowsum,
                        const int* __restrict__ vind, const float* __restrict__ hbuf,
                        const float* __restrict__ w2, float* __restrict__ out,
                        float* __restrict__ h2r0, int* __restrict__ done) {
    const int lane = threadIdx.x & 63;
    const int wv   = threadIdx.x >> 6;              // 0..15

    if (blockIdx.x >= 128) {                        // --- r0 reduction blocks ---
        __shared__ int is_last;
        const int wg = (blockIdx.x - 128) * 16 + wv; // 0..255
        float acc = 0.f;
        for (int t = wg; t < NT_; t += 256) {
            const int vc = vind[2 * t + 1];
            acc += lat2[t] * hbuf[vc * 64 + lane];
        }
        acc /= rowsum[0];
        atomicAdd(&h2r0[lane], acc);
        __threadfence();
        __syncthreads();                            // all waves' atomics done
        if (threadIdx.x == 0) is_last = (atomicAdd(done, 1) == 15);
        __syncthreads();
        if (is_last) {
            __threadfence();                        // acquire h2r0 writes
            if (threadIdx.x < 16) {
                const int c = threadIdx.x;
                float acc2 = 0.f;
                #pragma unroll
                for (int hh = 0; hh < 64; ++hh) acc2 += w2[hh * 16 + c] * h2r0[hh];
                atomicAdd(&out[c], acc2);
            }
        }
        return;
    }

    __shared__ float sw2[16384];                    // [rp][hh][c], 64KB
    for (int i = threadIdx.x; i < 16384; i += 1024) sw2[i] = w2[i];
    __syncthreads();

    const int c = lane & 15;
    const int quarter = lane >> 4;
    for (int e = blockIdx.x * 16 + wv; e < 120000; e += 128 * 16) {
        const int k  = NT_ + e;
        const int q  = vind[2 * k];
        const int vc = vind[2 * k + 1];
        const float val = lat2[k] / rowsum[q];
        const int rp = q / N_;
        const int np = q - rp * N_;
        const float u = val * hbuf[vc * 64 + lane]; // coalesced 256B row
        float partial = 0.f;
        #pragma unroll
        for (int j = 0; j < 16; ++j) {
            const int hh = quarter * 16 + ((j + quarter) & 15);
            const float hv = __shfl(u, hh);
            partial += hv * sw2[rp * 1024 + hh * 16 + c];
        }
        partial += __shfl_xor(partial, 16);
        partial += __shfl_xor(partial, 32);
        if (quarter == 0) atomicAdd(&out[np * 16 + c], partial);
    }
}

extern "C" void kernel_launch(void* const* d_in, const int* in_sizes, int n_in,
                              void* d_out, int out_size, void* d_ws, size_t ws_size,
                              hipStream_t stream) {
    const float* nhots    = (const float*)d_in[0];
    const float* w1a      = (const float*)d_in[1];
    const float* b1a      = (const float*)d_in[2];
    const float* w1b      = (const float*)d_in[3];
    const float* b1b      = (const float*)d_in[4];
    const float* w2a      = (const float*)d_in[5];
    const float* b2a      = (const float*)d_in[6];
    const float* w2b      = (const float*)d_in[7];
    const float* b2b      = (const float*)d_in[8];
    const float* weights1 = (const float*)d_in[9];
    const float* bias1    = (const float*)d_in[10];
    const float* weights2 = (const float*)d_in[11];
    const float* bias2    = (const float*)d_in[12];
    const int*   hind     = (const int*)d_in[13];
    const int*   vind     = (const int*)d_in[14];
    float* out = (float*)d_out;

    float* ws     = (float*)d_ws;
    float* colsum = ws;
    float* rowsum = ws + 160000;
    float* h2r0   = ws + 320000;
    int*   cnt    = (int*)(ws + 320064);
    int*   done   = (int*)(ws + 330064);
    int*   order2 = (int*)(ws + 330080);
    float* hbuf   = ws + 650080;
    float* lat1t  = ws + 1290080;
    float* lat2   = ws + 1418080;

    hipMemsetAsync(d_ws, 0, WS_ZERO_UNITS * sizeof(float), stream);
    k_lat<<<2000, 256, 0, stream>>>(nhots, w1a, b1a, w1b, b1b, w2a, b2a, w2b, b2b,
                                    hind, vind, lat1t, lat2, colsum, rowsum, cnt,
                                    order2, out, bias2);
    k_hg<<<2500, 256, 0, stream>>>(lat1t, colsum, cnt, order2, weights1, bias1, hbuf);
    k_h2all<<<144, 1024, 0, stream>>>(lat2, rowsum, vind, hbuf, weights2, out, h2r0, done);
}

// Round 8
// 415.812 us; speedup vs baseline: 1.1113x; 1.0761x over previous
//
#include <hip/hip_runtime.h>
#include <hip/hip_bf16.h>

// LGCN2: N=10000 nodes, RP=16, E=LW=64, R=NT=8000 edges, C=16, NREL=50.
// Round 8: R7 + k_h2all grid 144 -> 256 blocks (240 compute + 16 r0).
// At 64KB LDS only 2 blocks/CU fit; 144 blocks left 112 CUs idle. 256 blocks
// = 1 block/CU, edge loop parallelism 2x. vind loaded as int2.

#define N_     10000
#define RP_    16
#define E_     64
#define R_     8000
#define NT_    8000
#define C_     16
#define BK_    32              // s-bucket capacity; max s-degree (Poisson 0.8) << 32

// ---- workspace layout (4-byte units) ----
// colsum  [0,       160000)  f  (zeroed)
// rowsum  [160000,  320000)  f  (zeroed)
// h2r0    [320000,  320064)  f  (zeroed)
// cnt     [320064,  330064)  i  (zeroed)
// done    [330064,  330065)  i  (zeroed)
// order2  [330080,  650080)  i  (t | o<<13; guarded by cnt)
// hbuf    [650080, 1290080)  f  (written, no zero needed)
// lat1t   [1290080,1418080)  f  [t*16+r] layout (gather broadcast reads)
// lat2    [1418080,1546080)  f  [r*8000+t] k-order (stage-2 coalescing)
#define WS_ZERO_UNITS 330080

__global__ void k_lat(const float* __restrict__ nhots,
                      const float* __restrict__ w1a, const float* __restrict__ b1a,
                      const float* __restrict__ w1b, const float* __restrict__ b1b,
                      const float* __restrict__ w2a, const float* __restrict__ b2a,
                      const float* __restrict__ w2b, const float* __restrict__ b2b,
                      const int* __restrict__ hind, const int* __restrict__ vind,
                      float* __restrict__ lat1t, float* __restrict__ lat2,
                      float* __restrict__ colsum, float* __restrict__ rowsum,
                      int* __restrict__ cnt, int* __restrict__ order2,
                      float* __restrict__ out, const float* __restrict__ bias2) {
    __shared__ float zb[4][128];
    __shared__ float r0[2];
    const int lane = threadIdx.x & 63;
    const int wv   = threadIdx.x >> 6;
    const int t    = blockIdx.x * 4 + wv;          // 2000*4 == 8000 exactly

    // fused out-init: 2000 blocks * 80 == 160000 exactly
    if (threadIdx.x < 80) {
        const int i = blockIdx.x * 80 + threadIdx.x;
        out[i] = bias2[i & 15];
    }

    // --- sparse gather: scan first 64 columns (hot col < NREL=50 < 64) ---
    const float v = nhots[(size_t)t * R_ + lane];
    float acc1 = 0.f, acc2 = 0.f;
    unsigned long long m = __ballot(v != 0.0f);
    while (m) {
        const int src = __ffsll(m) - 1;
        m &= m - 1;
        const float val = __shfl(v, src);
        acc1 += val * w1a[src * 64 + lane];
        acc2 += val * w2a[src * 64 + lane];
    }
    if (threadIdx.x == 0) { r0[0] = 0.f; r0[1] = 0.f; }
    zb[wv][lane]      = fmaxf(acc1 + b1a[lane], 0.f);
    zb[wv][64 + lane] = fmaxf(acc2 + b2a[lane], 0.f);
    __syncthreads();

    // --- 64->16 dense layer: lanes 0..15 do lat1, 16..31 do lat2 ---
    const int g = lane >> 4, r = lane & 15;
    float pre = 0.f;
    if (g < 2) {
        const float* wb = (g == 0) ? w1b : w2b;
        pre = ((g == 0) ? b1b : b2b)[r];
        const float* z = &zb[wv][g * 64];
        #pragma unroll
        for (int l = 0; l < 64; ++l) pre += z[l] * wb[l * 16 + r];
    }
    // --- softmax over the 16-lane group ---
    float mx = pre;
    #pragma unroll
    for (int mm = 8; mm >= 1; mm >>= 1) mx = fmaxf(mx, __shfl_xor(mx, mm, 16));
    const float e = expf(pre - mx);
    float s = e;
    #pragma unroll
    for (int mm = 8; mm >= 1; mm >>= 1) s += __shfl_xor(s, mm, 16);
    const float lt = e / s;

    const int s_t = hind[2 * t];                   // r=0 band: hrow == s[t]
    const int o_t = vind[2 * t + 1];               // r=0 band: vcol == o[t]
    if (g == 0) {
        lat1t[t * 16 + r] = lt;
        if (r) atomicAdd(colsum + o_t * r, lt);    // key hcol == o*r
        else   atomicAdd(&r0[0], lt);              // key-0 hotspot -> LDS pre-agg
    } else if (g == 1) {
        lat2[r * NT_ + t] = lt;
        if (r) atomicAdd(rowsum + s_t * r, lt);
        else   atomicAdd(&r0[1], lt);
    } else if (g == 2 && r == 0) {                 // idle lane: bucket insert
        const int pos = atomicAdd(cnt + s_t, 1);
        order2[s_t * BK_ + pos] = t | (o_t << 13); // t < 8192
    }
    __syncthreads();
    if (threadIdx.x == 0) atomicAdd(colsum, r0[0]);
    if (threadIdx.x == 1) atomicAdd(rowsum, r0[1]);
}

// gather: one wave per node n; h[n,l] = relu(bias1[l] + sum_{t in n} sum_r
//   (lat1[r,t]/colsum[o_t*r]) * weights1[o_t*r, l])
__global__ void k_hg(const float* __restrict__ lat1t, const float* __restrict__ colsum,
                     const int* __restrict__ cnt, const int* __restrict__ order2,
                     const float* __restrict__ w1,
                     const float* __restrict__ bias1, float* __restrict__ hbuf) {
    const int lane = threadIdx.x & 63;
    const int n = blockIdx.x * 4 + (threadIdx.x >> 6);  // 2500*4 == 10000 exactly
    const int m = cnt[n];
    float acc = 0.f;
    for (int j = 0; j < m; ++j) {
        const int e = order2[n * BK_ + j];
        const int t   = e & 8191;
        const int o_t = e >> 13;
        float ln = 0.f;
        if (lane < 16) ln = lat1t[t * 16 + lane] / colsum[o_t * lane];
        #pragma unroll
        for (int r = 0; r < 16; ++r) {
            const float a = __shfl(ln, r);
            acc += a * w1[(o_t * r) * 64 + lane];   // coalesced 256B row
        }
    }
    hbuf[n * 64 + lane] = fmaxf(acc + bias1[lane], 0.f);
}

// Stage 2, one dispatch, 1024-thread blocks, 256 blocks (1/CU):
//  blocks 0..239  : generic edges (k>=8000), wave-per-edge. hbuf row loaded
//                   once coalesced; w2 in LDS (quarter-staggered shfl reduce).
//  blocks 240..255: r=0 band (16 waves each; 256 partials) block reduction
//                   into h2r0; LAST r0 block (ticket==15) applies w2[0]·h2r0.
__global__ void k_h2all(const float* __restrict__ lat2, const float* __restrict__ rowsum,
                        const int* __restrict__ vind, const float* __restrict__ hbuf,
                        const float* __restrict__ w2, float* __restrict__ out,
                        float* __restrict__ h2r0, int* __restrict__ done) {
    const int lane = threadIdx.x & 63;
    const int wv   = threadIdx.x >> 6;              // 0..15

    if (blockIdx.x >= 240) {                        // --- r0 reduction blocks ---
        __shared__ int is_last;
        const int wg = (blockIdx.x - 240) * 16 + wv; // 0..255
        float acc = 0.f;
        for (int t = wg; t < NT_; t += 256) {
            const int vc = vind[2 * t + 1];
            acc += lat2[t] * hbuf[vc * 64 + lane];
        }
        acc /= rowsum[0];
        atomicAdd(&h2r0[lane], acc);
        __threadfence();
        __syncthreads();                            // all waves' atomics done
        if (threadIdx.x == 0) is_last = (atomicAdd(done, 1) == 15);
        __syncthreads();
        if (is_last) {
            __threadfence();                        // acquire h2r0 writes
            if (threadIdx.x < 16) {
                const int c = threadIdx.x;
                float acc2 = 0.f;
                #pragma unroll
                for (int hh = 0; hh < 64; ++hh) acc2 += w2[hh * 16 + c] * h2r0[hh];
                atomicAdd(&out[c], acc2);
            }
        }
        return;
    }

    __shared__ float sw2[16384];                    // [rp][hh][c], 64KB
    for (int i = threadIdx.x; i < 16384; i += 1024) sw2[i] = w2[i];
    __syncthreads();

    const int c = lane & 15;
    const int quarter = lane >> 4;
    for (int e = blockIdx.x * 16 + wv; e < 120000; e += 240 * 16) {
        const int k  = NT_ + e;
        const int2 vv = reinterpret_cast<const int2*>(vind)[k];
        const int q  = vv.x;
        const int vc = vv.y;
        const float val = lat2[k] / rowsum[q];
        const int rp = q / N_;
        const int np = q - rp * N_;
        const float u = val * hbuf[vc * 64 + lane]; // coalesced 256B row
        float partial = 0.f;
        #pragma unroll
        for (int j = 0; j < 16; ++j) {
            const int hh = quarter * 16 + ((j + quarter) & 15);
            const float hv = __shfl(u, hh);
            partial += hv * sw2[rp * 1024 + hh * 16 + c];
        }
        partial += __shfl_xor(partial, 16);
        partial += __shfl_xor(partial, 32);
        if (quarter == 0) atomicAdd(&out[np * 16 + c], partial);
    }
}

extern "C" void kernel_launch(void* const* d_in, const int* in_sizes, int n_in,
                              void* d_out, int out_size, void* d_ws, size_t ws_size,
                              hipStream_t stream) {
    const float* nhots    = (const float*)d_in[0];
    const float* w1a      = (const float*)d_in[1];
    const float* b1a      = (const float*)d_in[2];
    const float* w1b      = (const float*)d_in[3];
    const float* b1b      = (const float*)d_in[4];
    const float* w2a      = (const float*)d_in[5];
    const float* b2a      = (const float*)d_in[6];
    const float* w2b      = (const float*)d_in[7];
    const float* b2b      = (const float*)d_in[8];
    const float* weights1 = (const float*)d_in[9];
    const float* bias1    = (const float*)d_in[10];
    const float* weights2 = (const float*)d_in[11];
    const float* bias2    = (const float*)d_in[12];
    const int*   hind     = (const int*)d_in[13];
    const int*   vind     = (const int*)d_in[14];
    float* out = (float*)d_out;

    float* ws     = (float*)d_ws;
    float* colsum = ws;
    float* rowsum = ws + 160000;
    float* h2r0   = ws + 320000;
    int*   cnt    = (int*)(ws + 320064);
    int*   done   = (int*)(ws + 330064);
    int*   order2 = (int*)(ws + 330080);
    float* hbuf   = ws + 650080;
    float* lat1t  = ws + 1290080;
    float* lat2   = ws + 1418080;

    hipMemsetAsync(d_ws, 0, WS_ZERO_UNITS * sizeof(float), stream);
    k_lat<<<2000, 256, 0, stream>>>(nhots, w1a, b1a, w1b, b1b, w2a, b2a, w2b, b2b,
                                    hind, vind, lat1t, lat2, colsum, rowsum, cnt,
                                    order2, out, bias2);
    k_hg<<<2500, 256, 0, stream>>>(lat1t, colsum, cnt, order2, weights1, bias1, hbuf);
    k_h2all<<<256, 1024, 0, stream>>>(lat2, rowsum, vind, hbuf, weights2, out, h2r0, done);
}